// Round 1
// baseline (348.513 us; speedup 1.0000x reference)
//
#include <hip/hip_runtime.h>
#include <math.h>

#define BDIM 64
#define NCAP 10
#define IC 6912
#define ID 16
#define OD 16
#define JB 16
#define NBLK (IC / JB)   // 432 blocks
#define SPART_STRIDE (BDIM * NCAP * OD)  // 10240 floats per partial image
#define VS_PAD 164       // padded per-b stride for vsum LDS (164 % 32 = 4 -> no bank conflict)

// One routing sweep: recompute u_hat tiles in registers, apply routing weights,
// accumulate per-block partial s into s_part[blockIdx][10240].
// iter==0: c = 0.1 uniform (softmax of zeros). iter>0: bb = u . vsum, softmax over n.
__global__ __launch_bounds__(256, 2) void sweep_kernel(
    const float* __restrict__ x, const float* __restrict__ W,
    const float* __restrict__ vsum, float* __restrict__ s_part, int iter)
{
    __shared__ float w_s[NCAP * ID * OD];   // 2560 floats: W[:, j, :, :]
    __shared__ float x_s[BDIM * ID];        // 1024 floats: x[:, j, :]
    __shared__ float vs_s[BDIM * VS_PAD];   // padded vsum tile

    const int tid = threadIdx.x;
    const int b   = tid >> 2;   // 0..63
    const int oq  = tid & 3;    // o-quad: owns o = oq*4 .. oq*4+3
    const int j0  = blockIdx.x * JB;

    if (iter > 0) {
        for (int idx = tid; idx < BDIM * NCAP * OD; idx += 256) {
            int bb_ = idx / (NCAP * OD);
            int r   = idx - bb_ * (NCAP * OD);
            vs_s[bb_ * VS_PAD + r] = vsum[idx];
        }
    }

    float4 sac[NCAP];
    #pragma unroll
    for (int n = 0; n < NCAP; ++n) sac[n] = make_float4(0.f, 0.f, 0.f, 0.f);

    for (int jj = 0; jj < JB; ++jj) {
        const int j = j0 + jj;
        __syncthreads();  // protect previous iteration's w_s/x_s reads

        // stage W[:, j, :, :] (2560 floats) — coalesced
        {
            const float* wp = W + (size_t)j * (ID * OD);
            #pragma unroll
            for (int r = 0; r < NCAP; ++r)
                w_s[r * 256 + tid] = wp[(size_t)r * IC * (ID * OD) + tid];
        }
        // stage x[:, j, :] (1024 floats) — coalesced
        {
            const float* xp = x + (size_t)j * ID;
            #pragma unroll
            for (int r = 0; r < 4; ++r) {
                int idx = r * 256 + tid;
                x_s[idx] = xp[(size_t)(idx >> 4) * (IC * ID) + (idx & 15)];
            }
        }
        __syncthreads();

        // x[b, j, :] -> 16 registers
        float4 xr[4];
        #pragma unroll
        for (int r = 0; r < 4; ++r)
            xr[r] = *(const float4*)&x_s[b * ID + r * 4];

        // u_hat[b, n, j, oq*4..+3] for all n, in registers
        float4 u[NCAP];
        #pragma unroll
        for (int n = 0; n < NCAP; ++n) {
            float4 acc = make_float4(0.f, 0.f, 0.f, 0.f);
            #pragma unroll
            for (int r = 0; r < 4; ++r) {
                const float xv[4] = { xr[r].x, xr[r].y, xr[r].z, xr[r].w };
                #pragma unroll
                for (int t = 0; t < 4; ++t) {
                    int i = r * 4 + t;
                    float4 wv = *(const float4*)&w_s[(n * ID + i) * OD + oq * 4];
                    acc.x = fmaf(xv[t], wv.x, acc.x);
                    acc.y = fmaf(xv[t], wv.y, acc.y);
                    acc.z = fmaf(xv[t], wv.z, acc.z);
                    acc.w = fmaf(xv[t], wv.w, acc.w);
                }
            }
            u[n] = acc;
        }

        // routing weights c[n]
        float c[NCAP];
        if (iter == 0) {
            #pragma unroll
            for (int n = 0; n < NCAP; ++n) c[n] = 0.1f;
        } else {
            float bb[NCAP];
            #pragma unroll
            for (int n = 0; n < NCAP; ++n) {
                float4 vv = *(const float4*)&vs_s[b * VS_PAD + n * OD + oq * 4];
                float d = u[n].x * vv.x + u[n].y * vv.y + u[n].z * vv.z + u[n].w * vv.w;
                d += __shfl_xor(d, 1);   // oq lives in lane bits 0..1
                d += __shfl_xor(d, 2);
                bb[n] = d;               // full dot over all 16 o
            }
            float m = bb[0];
            #pragma unroll
            for (int n = 1; n < NCAP; ++n) m = fmaxf(m, bb[n]);
            float ssum = 0.f;
            #pragma unroll
            for (int n = 0; n < NCAP; ++n) { c[n] = __expf(bb[n] - m); ssum += c[n]; }
            float inv = 1.0f / ssum;
            #pragma unroll
            for (int n = 0; n < NCAP; ++n) c[n] *= inv;
        }

        // s[b,n,o] += c[b,n,j] * u_hat[b,n,j,o]
        #pragma unroll
        for (int n = 0; n < NCAP; ++n) {
            sac[n].x = fmaf(c[n], u[n].x, sac[n].x);
            sac[n].y = fmaf(c[n], u[n].y, sac[n].y);
            sac[n].z = fmaf(c[n], u[n].z, sac[n].z);
            sac[n].w = fmaf(c[n], u[n].w, sac[n].w);
        }
    }

    // write block-partial s image
    float* sp = s_part + (size_t)blockIdx.x * SPART_STRIDE;
    #pragma unroll
    for (int n = 0; n < NCAP; ++n)
        *(float4*)&sp[(b * NCAP + n) * OD + oq * 4] = sac[n];
}

// Reduce partials over blocks, squash, maintain vsum, write final output.
// grid 40 x 256 threads; thread g = (b*N + n)*OD + o.
__global__ __launch_bounds__(256) void reduce_squash_kernel(
    const float* __restrict__ s_part, float* __restrict__ vsum,
    float* __restrict__ out, int iter)
{
    const int g = blockIdx.x * 256 + threadIdx.x;  // 0..10239
    float acc = 0.f;
    for (int k = 0; k < NBLK; ++k)
        acc += s_part[(size_t)k * SPART_STRIDE + g];

    // squash over the 16 o's (o = lane bits 0..3)
    float sq = acc * acc;
    sq += __shfl_xor(sq, 1);
    sq += __shfl_xor(sq, 2);
    sq += __shfl_xor(sq, 4);
    sq += __shfl_xor(sq, 8);
    float scale = (sq / (1.f + sq)) / sqrtf(sq + 1e-7f);
    float v = scale * acc;

    if (iter == 2) {
        out[g] = v;           // final output v3, layout [B, N, OD]
    } else if (iter == 0) {
        vsum[g] = v;          // vsum = v1 (overwrites 0xAA poison)
    } else {
        vsum[g] += v;         // vsum = v1 + v2
    }
}

extern "C" void kernel_launch(void* const* d_in, const int* in_sizes, int n_in,
                              void* d_out, int out_size, void* d_ws, size_t ws_size,
                              hipStream_t stream) {
    (void)in_sizes; (void)n_in; (void)out_size; (void)ws_size;
    const float* x = (const float*)d_in[0];   // [64, 6912, 16]
    const float* W = (const float*)d_in[1];   // [10, 6912, 16, 16]
    float* out = (float*)d_out;               // [64, 10, 16]

    float* s_part = (float*)d_ws;                               // 432 * 10240 floats
    float* vsum   = s_part + (size_t)NBLK * SPART_STRIDE;       // 10240 floats

    for (int iter = 0; iter < 3; ++iter) {
        sweep_kernel<<<NBLK, 256, 0, stream>>>(x, W, vsum, s_part, iter);
        reduce_squash_kernel<<<40, 256, 0, stream>>>(s_part, vsum, out, iter);
    }
}